// Round 12
// baseline (232.705 us; speedup 1.0000x reference)
//
#include <hip/hip_runtime.h>
#include <hip/hip_bf16.h>
#include <math.h>

// ---------------------------------------------------------------------------
// MultiHeadAttention: B=4, S=2048, D=1024, H=16, Dh=64, causal. fp32 I/O.
// R19: revert attn staging to R17 (double-buffer + one __syncthreads/iter;
//      R18's counted-vmcnt 3-slot pipeline regressed ~borderline: latency
//      was already hidden, machinery added overhead) + T5 s_setprio(1/0)
//      around attn's MFMA clusters (waves have role diversity between
//      barriers: stage-issue vs exp2/pack vs MFMA -> scheduler can favor
//      MFMA waves; m191 attn +4-7%).
//      qkv (R15 128^2 BK=64), bt (pipe-A), prep: byte-identical to R17.
// Scratch: ws[0:16M)=q/ctx, [16:32M)=k, [32:48M)=vT, [48:50M)=woT;
//   d_out 32MB fp32 buffer holds xb(16M)+wcatT(6M), consumed pre-final-GEMM.
// ---------------------------------------------------------------------------

typedef __attribute__((ext_vector_type(8))) short short8;   // 8 bf16 = 4 VGPRs
typedef __attribute__((ext_vector_type(4))) float f32x4;

#define MFMA_BF16(a, b, c) __builtin_amdgcn_mfma_f32_16x16x32_bf16((a), (b), (c), 0, 0, 0)

#define SBAR() asm volatile("s_barrier" ::: "memory")
#define VMCNT6() asm volatile("s_waitcnt vmcnt(6)" ::: "memory")
#define VMCNT0() asm volatile("s_waitcnt vmcnt(0)" ::: "memory")

__device__ __forceinline__ void gld_lds16(const void* g, void* l) {
  __builtin_amdgcn_global_load_lds((const __attribute__((address_space(1))) void*)g,
                                   (__attribute__((address_space(3))) void*)l, 16, 0, 0);
}

// ------------- merged prep: cast x -> bf16  +  transpose 4 weights ----------
// grid x: [0,8192) cast blocks; [8192, 8192+4096) transpose blocks.
__global__ void prep_kernel(const float* __restrict__ x, __hip_bfloat16* __restrict__ xb,
                            const float* __restrict__ W0, const float* __restrict__ W1,
                            const float* __restrict__ W2, const float* __restrict__ W3,
                            __hip_bfloat16* __restrict__ T0, __hip_bfloat16* __restrict__ T1,
                            __hip_bfloat16* __restrict__ T2, __hip_bfloat16* __restrict__ T3) {
  const int bid = blockIdx.x, tid = threadIdx.x;
  if (bid < 8192) {  // cast: 8192 blocks x 256 threads x 1 float4
    int i = bid * 256 + tid;
    float4 v = ((const float4*)x)[i];
    __align__(8) __hip_bfloat16 tmp[4] = {__float2bfloat16(v.x), __float2bfloat16(v.y),
                                          __float2bfloat16(v.z), __float2bfloat16(v.w)};
    ((ushort4*)xb)[i] = *(const ushort4*)tmp;
  } else {           // transpose: 4096 blocks (4 weights x 32 x 32 tiles)
    int zz = bid - 8192;
    int z = zz >> 10, rem = zz & 1023;
    const float* W = (z == 0) ? W0 : (z == 1) ? W1 : (z == 2) ? W2 : W3;
    __hip_bfloat16* Wt = (z == 0) ? T0 : (z == 1) ? T1 : (z == 2) ? T2 : T3;
    __shared__ float tile[32][33];
    int tx = tid & 31, ty = tid >> 5;                // (32,8)
    int n0 = (rem & 31) * 32, k0 = (rem >> 5) * 32;
#pragma unroll
    for (int i = 0; i < 4; ++i)
      tile[ty + i * 8][tx] = W[(size_t)(k0 + ty + i * 8) * 1024 + n0 + tx];
    __syncthreads();
#pragma unroll
    for (int i = 0; i < 4; ++i)
      Wt[(size_t)(n0 + ty + i * 8) * 1024 + k0 + tx] = __float2bfloat16(tile[tx][ty + i * 8]);
  }
}

// ------------- fused QKV GEMM over wcatT[3072][1024]; V written transposed ---
// grid (24, 64): part = x>>3 (0=q,1=k,2=v). 128x128 tiles, BK=64, K=1024.
// LDS: [128 rows][8 chunks of 16B], chunk XOR-swizzled by row&7.
// Q output pre-scaled by CSCL = (1/sqrt(64))*log2(e).
// V rows written sigma-PERMUTED within each 64-block (attn in-register P
// map): true offset mt*16+quad*4+r -> column (mt>>1)*32+quad*8+(mt&1)*4+r.
__global__ __launch_bounds__(256, 2) void gemm_qkv(
    const __hip_bfloat16* __restrict__ A, const __hip_bfloat16* __restrict__ Bt,
    __hip_bfloat16* __restrict__ q, __hip_bfloat16* __restrict__ k,
    __hip_bfloat16* __restrict__ vT) {
  __shared__ __align__(16) __hip_bfloat16 As[128 * 64];
  __shared__ __align__(16) __hip_bfloat16 Bs[128 * 64];
  const int tid = threadIdx.x;
  const int lane = tid & 63, wid = tid >> 6;
  const int quad = lane >> 4, l16 = lane & 15;
  const int part = blockIdx.x >> 3;
  const int n0 = (blockIdx.x & 7) * 128;
  const int gn0 = part * 1024 + n0;
  const int m0 = blockIdx.y * 128;
  const int wm = (wid & 1) * 64, wn = (wid >> 1) * 64;
  const int swz = l16 & 7;                    // row&7 for all fragment rows

  f32x4 acc[4][4] = {};

  for (int k0 = 0; k0 < 1024; k0 += 64) {
    __syncthreads();
#pragma unroll
    for (int i = 0; i < 4; ++i) {
      int sbase = __builtin_amdgcn_readfirstlane(wid * 256 + i * 64);
      int s = sbase + lane;                   // slot: row = s>>3, ch_phys = s&7
      int row = s >> 3;
      int ch = (s & 7) ^ (row & 7);           // logical chunk this slot holds
      gld_lds16(A + (size_t)(m0 + row) * 1024 + k0 + ch * 8, &As[sbase * 8]);
      gld_lds16(Bt + (size_t)(gn0 + row) * 1024 + k0 + ch * 8, &Bs[sbase * 8]);
    }
    __syncthreads();

    short8 af[4][2], bfr[4][2];
#pragma unroll
    for (int t = 0; t < 4; ++t)
#pragma unroll
      for (int kc = 0; kc < 2; ++kc) {
        int chp = (kc * 4 + quad) ^ swz;      // swizzled chunk
        af[t][kc]  = *(const short8*)&As[(wm + t * 16 + l16) * 64 + chp * 8];
        bfr[t][kc] = *(const short8*)&Bs[(wn + t * 16 + l16) * 64 + chp * 8];
      }
#pragma unroll
    for (int kc = 0; kc < 2; ++kc)
#pragma unroll
      for (int mt = 0; mt < 4; ++mt)
#pragma unroll
        for (int nt = 0; nt < 4; ++nt)
          acc[mt][nt] = MFMA_BF16(af[mt][kc], bfr[nt][kc], acc[mt][nt]);
  }

  const float CSCL = 0.18033688011112042f;  // (1/sqrt(64)) * log2(e)
  if (part < 2) {
    __hip_bfloat16* C = (part == 0) ? q : k;
    const float scl = (part == 0) ? CSCL : 1.0f;
#pragma unroll
    for (int mt = 0; mt < 4; ++mt)
#pragma unroll
      for (int nt = 0; nt < 4; ++nt) {
        int row = m0 + wm + mt * 16 + quad * 4;
        int col = n0 + wn + nt * 16 + l16;
#pragma unroll
        for (int r = 0; r < 4; ++r)
          C[(size_t)(row + r) * 1024 + col] = __float2bfloat16(acc[mt][nt][r] * scl);
      }
  } else {
#pragma unroll
    for (int mt = 0; mt < 4; ++mt) {
      // sigma^{-1}: own-lane kpos run mt*16+quad*4+r lands at column
      // (mt>>1)*32 + quad*8 + (mt&1)*4 + r  (bijective within 64-block)
      int rowp = m0 + wm + (mt >> 1) * 32 + quad * 8 + (mt & 1) * 4;
#pragma unroll
      for (int nt = 0; nt < 4; ++nt) {
        int nn = n0 + wn + nt * 16 + l16;
        __align__(8) __hip_bfloat16 p4[4];
#pragma unroll
        for (int r = 0; r < 4; ++r) p4[r] = __float2bfloat16(acc[mt][nt][r]);
        *(ushort4*)(vT + (size_t)nn * 8192 + rowp) = *(const ushort4*)p4;
      }
    }
  }
}

// ---------------- pipe-A deep K-loop (K=1024, BK=64) for gemm_bt ------------
// BM=256,BN=128, 512 thr (8 waves 4Mx2N, per-wave 64x64). 3 LDS slots.
// Tile t in slot t%3, staged during tile t-2; vmcnt(6) once per tile.
__device__ __forceinline__ void gemm8p_kloop(
    const __hip_bfloat16* __restrict__ A, const __hip_bfloat16* __restrict__ Bt,
    int m0, int gn0, __hip_bfloat16* As_, __hip_bfloat16* Bs_,
    f32x4 (&acc)[4][4]) {
  const int tid = threadIdx.x;
  const int lane = tid & 63, wid = tid >> 6;
  const int quad = lane >> 4, l16 = lane & 15;
  const int wm = (wid >> 1) * 64, wn = (wid & 1) * 64;
  const int sw = l16 & 7;

  // stage one half (A: 2x16B, B: 1x16B per thread) of tile t into slot
  auto stage_half = [&](int t, int half, int slot) {
#pragma unroll
    for (int li = 0; li < 2; ++li) {
      int sbase = __builtin_amdgcn_readfirstlane((half * 2 + li) * 512 + wid * 64);
      int s = sbase + lane, row = s >> 3, ch = (s & 7) ^ (row & 7);
      gld_lds16(A + (size_t)(m0 + row) * 1024 + t * 64 + ch * 8,
                As_ + slot * 16384 + sbase * 8);
    }
    {
      int sbase = __builtin_amdgcn_readfirstlane(half * 512 + wid * 64);
      int s = sbase + lane, row = s >> 3, ch = (s & 7) ^ (row & 7);
      gld_lds16(Bt + (size_t)(gn0 + row) * 1024 + t * 64 + ch * 8,
                Bs_ + slot * 8192 + sbase * 8);
    }
  };

  // one tile = 2 phases. mode 0: stage tile t+2 + vmcnt(6) at end;
  // mode 1: no stage, vmcnt(0) at end; mode 2: tail, no stage/waits/barriers.
  auto tile_step = [&](int t, int cur, int st, int mode) {
    const __hip_bfloat16* Asl = As_ + cur * 16384;
    const __hip_bfloat16* Bsl = Bs_ + cur * 8192;
    short8 af[4][2], bf01[2][2], bf23[2][2];
    // ---- phase even: read A(all m) + B(n0,n1); stage half 0 ----
#pragma unroll
    for (int mt = 0; mt < 4; ++mt)
#pragma unroll
      for (int kc = 0; kc < 2; ++kc)
        af[mt][kc] = *(const short8*)&Asl[(wm + mt * 16 + l16) * 64 +
                                          (((kc * 4 + quad) ^ sw) << 3)];
#pragma unroll
    for (int nt = 0; nt < 2; ++nt)
#pragma unroll
      for (int kc = 0; kc < 2; ++kc)
        bf01[nt][kc] = *(const short8*)&Bsl[(wn + nt * 16 + l16) * 64 +
                                            (((kc * 4 + quad) ^ sw) << 3)];
    if (mode == 0) stage_half(t + 2, 0, st);
    if (mode != 2) SBAR();
    __builtin_amdgcn_s_setprio(1);
#pragma unroll
    for (int kc = 0; kc < 2; ++kc)
#pragma unroll
      for (int mt = 0; mt < 4; ++mt)
#pragma unroll
        for (int nt = 0; nt < 2; ++nt)
          acc[mt][nt] = MFMA_BF16(af[mt][kc], bf01[nt][kc], acc[mt][nt]);
    __builtin_amdgcn_s_setprio(0);
    if (mode != 2) SBAR();
    // ---- phase odd: read B(n2,n3); stage half 1 ----
#pragma unroll
    for (int nt = 0; nt < 2; ++nt)
#pragma unroll
      for (int kc = 0; kc < 2; ++kc)
        bf23[nt][kc] = *(const short8*)&Bsl[(wn + (2 + nt) * 16 + l16) * 64 +
                                            (((kc * 4 + quad) ^ sw) << 3)];
    if (mode == 0) stage_half(t + 2, 1, st);
    if (mode != 2) SBAR();
    __builtin_amdgcn_s_setprio(1);
#pragma unroll
    for (int kc = 0; kc < 2; ++kc)
#pragma unroll
      for (int mt = 0; mt < 4; ++mt)
#pragma unroll
        for (int nt = 0; nt < 2; ++nt)
          acc[mt][2 + nt] = MFMA_BF16(af[mt][kc], bf23[nt][kc], acc[mt][2 + nt]);
    __builtin_amdgcn_s_setprio(0);
    if (mode == 0) VMCNT6();
    if (mode == 1) VMCNT0();
    if (mode != 2) SBAR();
  };

  // prologue: stage tile 0 -> slot 0, tile 1 -> slot 1 (6 loads each)
#pragma unroll
  for (int h = 0; h < 2; ++h) stage_half(0, h, 0);
#pragma unroll
  for (int h = 0; h < 2; ++h) stage_half(1, h, 1);
  VMCNT6();   // 12 in flight -> wait for oldest 6 = tile 0 landed
  SBAR();

  int cur = 0, st = 2;
#pragma unroll 1
  for (int t = 0; t < 14; ++t) {
    tile_step(t, cur, st, 0);
    cur = (cur == 2) ? 0 : cur + 1;
    st = (st == 2) ? 0 : st + 1;
  }
  tile_step(14, 2, 0, 1);   // drain remaining (tile 15) loads at end
  tile_step(15, 0, 0, 2);   // pure compute, no syncs needed after
}

// --------------- final GEMM: out = ctx * woT^T + bias (fp32 out) -----------
// grid (8, 32): n0 = x*128, m0 = y*256 -> 256 blocks = exactly 1 round.
__global__ __launch_bounds__(512, 2) void gemm_bt_f32out(
    const __hip_bfloat16* __restrict__ A, const __hip_bfloat16* __restrict__ Bt,
    float* __restrict__ C, const float* __restrict__ bias) {
  __shared__ __align__(16) __hip_bfloat16 As[3 * 256 * 64];
  __shared__ __align__(16) __hip_bfloat16 Bs[3 * 128 * 64];
  const int tid = threadIdx.x;
  const int lane = tid & 63, wid = tid >> 6;
  const int quad = lane >> 4, l16 = lane & 15;
  const int n0 = blockIdx.x * 128, m0 = blockIdx.y * 256;
  const int wm = (wid >> 1) * 64, wn = (wid & 1) * 64;

  f32x4 acc[4][4] = {};
  gemm8p_kloop(A, Bt, m0, n0, As, Bs, acc);

#pragma unroll
  for (int mt = 0; mt < 4; ++mt)
#pragma unroll
    for (int nt = 0; nt < 4; ++nt) {
      int row = m0 + wm + mt * 16 + quad * 4;
      int col = n0 + wn + nt * 16 + l16;
      float b = bias[col];
#pragma unroll
      for (int r = 0; r < 4; ++r)
        C[(size_t)(row + r) * 1024 + col] = acc[mt][nt][r] + b;
    }
}

// ----------------------------- flash attention ------------------------------
// R19: R17 structure (16 q-tiles of 128 rows, paired (t,15-t), 34 uniform
// iters, grid 512, 4 waves x 32 q-rows; swapped QK^T; sigma in-register P,
// no ds_writes; double-buffered K/V staging, one __syncthreads/iter) +
// T5 setprio(1) around the MFMA clusters.
__global__ __launch_bounds__(256, 2) void attn_kernel(
    const __hip_bfloat16* __restrict__ Q, const __hip_bfloat16* __restrict__ Km,
    const __hip_bfloat16* __restrict__ vT, __hip_bfloat16* __restrict__ ctx) {
  const int bid = blockIdx.x;
  // XCD-grouped remap: each XCD owns 8 full (b,h) streams (~4MB = its L2).
  const int xcd = bid & 7, loc = bid >> 3;
  const int grp = xcd * 8 + (loc >> 3);     // b*16 + h
  const int p = loc & 7;                    // pair index
  const int h = grp & 15, b = grp >> 4;
  const size_t rbase = (size_t)b * 2048;
  const int tid = threadIdx.x, lane = tid & 63, wid = tid >> 6;
  const int quad = lane >> 4, l16 = lane & 15;
  const int sw = l16 & 7;                   // fragment-row swizzle (row&7)

  __shared__ __align__(16) __hip_bfloat16 Ks[2][64 * 64];   // dbuf [kpos][swz]
  __shared__ __align__(16) __hip_bfloat16 Vs[2][64 * 64];   // dbuf [d][swz]

  const float NEG_BIG = -1e30f;             // exp2 -> exactly 0

#pragma unroll 1
  for (int sub = 0; sub < 2; ++sub) {
    const int t = sub ? (15 - p) : p;       // 128-row q-tile index
    const int q0 = t * 128;
    const int qw = q0 + wid * 32;           // wave's 32-row base
    const int nkt = 2 * t + 2;              // k-tiles this q-tile needs

    __syncthreads();  // all waves done reading LDS from previous sub
    {  // prologue: issue stage of k-tile 0 into buffer 0 (async)
#pragma unroll
      for (int i = 0; i < 2; ++i) {
        int sbase = __builtin_amdgcn_readfirstlane(i * 256 + wid * 64);
        int s = sbase + lane, row = s >> 3, lch = (s & 7) ^ (row & 7);
        gld_lds16(Km + (rbase + row) * 1024 + h * 64 + lch * 8, &Ks[0][sbase * 8]);
        gld_lds16(vT + (size_t)(h * 64 + row) * 8192 + rbase + lch * 8, &Vs[0][sbase * 8]);
      }
    }

    short8 qf[2][2];
#pragma unroll
    for (int mt = 0; mt < 2; ++mt)
#pragma unroll
      for (int kc = 0; kc < 2; ++kc)
        qf[mt][kc] = *(const short8*)(Q + (rbase + qw + mt * 16 + l16) * 1024 +
                                      h * 64 + kc * 32 + quad * 8);

    f32x4 o[2][4] = {};
    float lp[2] = {0.f, 0.f};               // per-lane row sums (row = l16)

#pragma unroll 1
    for (int kt = 0; kt < nkt; ++kt) {
      const int cur = kt & 1;
      const int kbase = kt * 64;
      // ONE barrier: stage(kt) landed (vmcnt drained by compiler here), and
      // all waves' reads of buf[cur^1] (iter kt-1) are done.
      __syncthreads();
      if (kt + 1 < nkt) {  // issue stage(kt+1) into the other buffer (async)
        const int kb = kbase + 64;
#pragma unroll
        for (int i = 0; i < 2; ++i) {
          int sbase = __builtin_amdgcn_readfirstlane(i * 256 + wid * 64);
          int s = sbase + lane, row = s >> 3, lch = (s & 7) ^ (row & 7);
          gld_lds16(Km + (rbase + kb + row) * 1024 + h * 64 + lch * 8,
                    &Ks[cur ^ 1][sbase * 8]);
          gld_lds16(vT + (size_t)(h * 64 + row) * 8192 + rbase + kb + lch * 8,
                    &Vs[cur ^ 1][sbase * 8]);
        }
      }
      const __hip_bfloat16* Kb = &Ks[cur][0];
      const __hip_bfloat16* Vb = &Vs[cur][0];

      if (kbase <= qw + 31) {  // wave-uniform: skip fully-masked tiles
        // K fragments (A-operand), reused for both mt
        short8 kf[4][2];
#pragma unroll
        for (int nt = 0; nt < 4; ++nt)
#pragma unroll
          for (int kc = 0; kc < 2; ++kc)
            kf[nt][kc] = *(const short8*)&Kb[(nt * 16 + l16) * 64 +
                                             (((kc * 4 + quad) ^ sw) << 3)];
        // S^T = K * Q^T: sv[mt][nt] has kpos=quad*4+r (+16nt), qrow=l16 (+16mt)
        f32x4 sv[2][4];
        __builtin_amdgcn_s_setprio(1);
#pragma unroll
        for (int mt = 0; mt < 2; ++mt)
#pragma unroll
          for (int nt = 0; nt < 4; ++nt) {
            f32x4 z = {0.f, 0.f, 0.f, 0.f};
            z = MFMA_BF16(kf[nt][0], qf[mt][0], z);
            z = MFMA_BF16(kf[nt][1], qf[mt][1], z);
            sv[mt][nt] = z;
          }
        __builtin_amdgcn_s_setprio(0);
        if (kbase + 63 > qw) {  // causal mask, diagonal-band tiles only
#pragma unroll
          for (int mt = 0; mt < 2; ++mt)
#pragma unroll
            for (int nt = 0; nt < 4; ++nt)
#pragma unroll
              for (int r = 0; r < 4; ++r) {
                int kpos = kbase + nt * 16 + quad * 4 + r;
                int qrow = qw + mt * 16 + l16;
                if (kpos > qrow) sv[mt][nt][r] = NEG_BIG;
              }
        }
        // p = exp2(s); assemble PV A-frags from OWN lane values only:
        // A-frag slot (kc, j) = p[nt = 2kc + (j>>2)][r = j&3]
        // (sigma k-reindex, matched by gemm_qkv's permuted vT columns).
        short8 pa[2][2];
#pragma unroll
        for (int mt = 0; mt < 2; ++mt)
#pragma unroll
          for (int kc = 0; kc < 2; ++kc) {
            __align__(16) __hip_bfloat16 pb[8];
#pragma unroll
            for (int half = 0; half < 2; ++half) {
              int nt = 2 * kc + half;
#pragma unroll
              for (int r = 0; r < 4; ++r) {
                float pv = __builtin_amdgcn_exp2f(sv[mt][nt][r]);
                lp[mt] += pv;
                pb[half * 4 + r] = __float2bfloat16(pv);
              }
            }
            pa[mt][kc] = *(const short8*)pb;
          }
        // PV: A = P (in-register), B = V (sigma-permuted tile), b128 reads
        short8 vf[4][2];
#pragma unroll
        for (int dt = 0; dt < 4; ++dt)
#pragma unroll
          for (int kc = 0; kc < 2; ++kc)
            vf[dt][kc] = *(const short8*)&Vb[(dt * 16 + l16) * 64 +
                                             (((kc * 4 + quad) ^ sw) << 3)];
        __builtin_amdgcn_s_setprio(1);
#pragma unroll
        for (int mt = 0; mt < 2; ++mt)
#pragma unroll
          for (int dt = 0; dt < 4; ++dt) {
            o[mt][dt] = MFMA_BF16(pa[mt][0], vf[dt][0], o[mt][dt]);
            o[mt][dt] = MFMA_BF16(pa[mt][1], vf[dt][1], o[mt][dt]);
          }
        __builtin_amdgcn_s_setprio(0);
      }
    }

    // lp[mt] holds partials for row mt*16+l16 spread across quads: reduce,
    // then redistribute to the C-layout rows (quad*4+r) via computed shfl.
#pragma unroll
    for (int mt = 0; mt < 2; ++mt) {
      lp[mt] += __shfl_xor(lp[mt], 16, 64);
      lp[mt] += __shfl_xor(lp[mt], 32, 64);
    }
#pragma unroll
    for (int mt = 0; mt < 2; ++mt) {
      float inv[4];
#pragma unroll
      for (int r = 0; r < 4; ++r)
        inv[r] = 1.f / __shfl(lp[mt], quad * 4 + r, 64);
#pragma unroll
      for (int dt = 0; dt < 4; ++dt)
#pragma unroll
        for (int r = 0; r < 4; ++r)
          ctx[(rbase + qw + mt * 16 + quad * 4 + r) * 1024 + h * 64 + dt * 16 + l16] =
              __float2bfloat16(o[mt][dt][r] * inv[r]);
    }
  }
}

// ------------------------------- launcher ----------------------------------
extern "C" void kernel_launch(void* const* d_in, const int* in_sizes, int n_in,
                              void* d_out, int out_size, void* d_ws, size_t ws_size,
                              hipStream_t stream) {
  const float* x  = (const float*)d_in[0];
  const float* Wq = (const float*)d_in[1];
  const float* Wk = (const float*)d_in[2];
  const float* Wv = (const float*)d_in[3];
  const float* Wo = (const float*)d_in[4];
  const float* bo = (const float*)d_in[5];
  float* out = (float*)d_out;

  char* ws = (char*)d_ws;
  const size_t MB = 1024ull * 1024ull;
  __hip_bfloat16* q   = (__hip_bfloat16*)(ws);             // 16 MB (reused as ctx)
  __hip_bfloat16* k   = (__hip_bfloat16*)(ws + 16 * MB);   // 16 MB
  __hip_bfloat16* vT  = (__hip_bfloat16*)(ws + 32 * MB);   // 16 MB, [h*64+d][b*2048+s]
  __hip_bfloat16* woT = (__hip_bfloat16*)(ws + 48 * MB);   // 2 MB -> 50 MB total
  __hip_bfloat16* ctx = q;  // attention reads its Q region before writing it

  // Pre-final scratch inside d_out's 32MB fp32 buffer (stream-ordered reuse):
  char* outc = (char*)d_out;
  __hip_bfloat16* xb    = (__hip_bfloat16*)(outc);            // [0, 16 MB)
  __hip_bfloat16* wcatT = (__hip_bfloat16*)(outc + 16 * MB);  // [16, 22 MB)

  prep_kernel<<<8192 + 4096, 256, 0, stream>>>(
      x, xb, Wq, Wk, Wv, Wo,
      wcatT, wcatT + 1024 * 1024, wcatT + 2048 * 1024, woT);

  gemm_qkv<<<dim3(24, 64), 256, 0, stream>>>(xb, wcatT, q, k, vT);

  attn_kernel<<<512, 256, 0, stream>>>(q, k, vT, ctx);

  gemm_bt_f32out<<<dim3(8, 32), 512, 0, stream>>>(ctx, woT, out, bo);
}

// Round 13
// 217.821 us; speedup vs baseline: 1.0683x; 1.0683x over previous
//
#include <hip/hip_runtime.h>
#include <hip/hip_bf16.h>
#include <math.h>

// ---------------------------------------------------------------------------
// MultiHeadAttention: B=4, S=2048, D=1024, H=16, Dh=64, causal. fp32 I/O.
// R20: byte-exact revert to R17 (measured best, 219.6us). R18 (counted-vmcnt
//      attn pipeline) and R19 (attn setprio) both regressed: R18's latency
//      was already hidden by the compute phase; R19's setprio needs
//      phase-diverse waves but attn's 4 waves are lockstep-barriered
//      (m190's negative case, not m191's positive one).
//      Components: qkv = 128^2 BK=64 2-barrier (858 TF, 97% of structure
//      ceiling); attn = swapped-QK + sigma in-register P (zero LDS/crosslane
//      for P) + double-buffered one-barrier staging; bt = pipe-A 256x128
//      deep pipeline (1-round grid); prep = cast+transpose merge.
// Scratch: ws[0:16M)=q/ctx, [16:32M)=k, [32:48M)=vT, [48:50M)=woT;
//   d_out 32MB fp32 buffer holds xb(16M)+wcatT(6M), consumed pre-final-GEMM.
// ---------------------------------------------------------------------------

typedef __attribute__((ext_vector_type(8))) short short8;   // 8 bf16 = 4 VGPRs
typedef __attribute__((ext_vector_type(4))) float f32x4;

#define MFMA_BF16(a, b, c) __builtin_amdgcn_mfma_f32_16x16x32_bf16((a), (b), (c), 0, 0, 0)

#define SBAR() asm volatile("s_barrier" ::: "memory")
#define VMCNT6() asm volatile("s_waitcnt vmcnt(6)" ::: "memory")
#define VMCNT0() asm volatile("s_waitcnt vmcnt(0)" ::: "memory")

__device__ __forceinline__ void gld_lds16(const void* g, void* l) {
  __builtin_amdgcn_global_load_lds((const __attribute__((address_space(1))) void*)g,
                                   (__attribute__((address_space(3))) void*)l, 16, 0, 0);
}

// ------------- merged prep: cast x -> bf16  +  transpose 4 weights ----------
// grid x: [0,8192) cast blocks; [8192, 8192+4096) transpose blocks.
__global__ void prep_kernel(const float* __restrict__ x, __hip_bfloat16* __restrict__ xb,
                            const float* __restrict__ W0, const float* __restrict__ W1,
                            const float* __restrict__ W2, const float* __restrict__ W3,
                            __hip_bfloat16* __restrict__ T0, __hip_bfloat16* __restrict__ T1,
                            __hip_bfloat16* __restrict__ T2, __hip_bfloat16* __restrict__ T3) {
  const int bid = blockIdx.x, tid = threadIdx.x;
  if (bid < 8192) {  // cast: 8192 blocks x 256 threads x 1 float4
    int i = bid * 256 + tid;
    float4 v = ((const float4*)x)[i];
    __align__(8) __hip_bfloat16 tmp[4] = {__float2bfloat16(v.x), __float2bfloat16(v.y),
                                          __float2bfloat16(v.z), __float2bfloat16(v.w)};
    ((ushort4*)xb)[i] = *(const ushort4*)tmp;
  } else {           // transpose: 4096 blocks (4 weights x 32 x 32 tiles)
    int zz = bid - 8192;
    int z = zz >> 10, rem = zz & 1023;
    const float* W = (z == 0) ? W0 : (z == 1) ? W1 : (z == 2) ? W2 : W3;
    __hip_bfloat16* Wt = (z == 0) ? T0 : (z == 1) ? T1 : (z == 2) ? T2 : T3;
    __shared__ float tile[32][33];
    int tx = tid & 31, ty = tid >> 5;                // (32,8)
    int n0 = (rem & 31) * 32, k0 = (rem >> 5) * 32;
#pragma unroll
    for (int i = 0; i < 4; ++i)
      tile[ty + i * 8][tx] = W[(size_t)(k0 + ty + i * 8) * 1024 + n0 + tx];
    __syncthreads();
#pragma unroll
    for (int i = 0; i < 4; ++i)
      Wt[(size_t)(n0 + ty + i * 8) * 1024 + k0 + tx] = __float2bfloat16(tile[tx][ty + i * 8]);
  }
}

// ------------- fused QKV GEMM over wcatT[3072][1024]; V written transposed ---
// grid (24, 64): part = x>>3 (0=q,1=k,2=v). 128x128 tiles, BK=64, K=1024.
// LDS: [128 rows][8 chunks of 16B], chunk XOR-swizzled by row&7.
// Q output pre-scaled by CSCL = (1/sqrt(64))*log2(e).
// V rows written sigma-PERMUTED within each 64-block (attn in-register P
// map): true offset mt*16+quad*4+r -> column (mt>>1)*32+quad*8+(mt&1)*4+r.
__global__ __launch_bounds__(256, 2) void gemm_qkv(
    const __hip_bfloat16* __restrict__ A, const __hip_bfloat16* __restrict__ Bt,
    __hip_bfloat16* __restrict__ q, __hip_bfloat16* __restrict__ k,
    __hip_bfloat16* __restrict__ vT) {
  __shared__ __align__(16) __hip_bfloat16 As[128 * 64];
  __shared__ __align__(16) __hip_bfloat16 Bs[128 * 64];
  const int tid = threadIdx.x;
  const int lane = tid & 63, wid = tid >> 6;
  const int quad = lane >> 4, l16 = lane & 15;
  const int part = blockIdx.x >> 3;
  const int n0 = (blockIdx.x & 7) * 128;
  const int gn0 = part * 1024 + n0;
  const int m0 = blockIdx.y * 128;
  const int wm = (wid & 1) * 64, wn = (wid >> 1) * 64;
  const int swz = l16 & 7;                    // row&7 for all fragment rows

  f32x4 acc[4][4] = {};

  for (int k0 = 0; k0 < 1024; k0 += 64) {
    __syncthreads();
#pragma unroll
    for (int i = 0; i < 4; ++i) {
      int sbase = __builtin_amdgcn_readfirstlane(wid * 256 + i * 64);
      int s = sbase + lane;                   // slot: row = s>>3, ch_phys = s&7
      int row = s >> 3;
      int ch = (s & 7) ^ (row & 7);           // logical chunk this slot holds
      gld_lds16(A + (size_t)(m0 + row) * 1024 + k0 + ch * 8, &As[sbase * 8]);
      gld_lds16(Bt + (size_t)(gn0 + row) * 1024 + k0 + ch * 8, &Bs[sbase * 8]);
    }
    __syncthreads();

    short8 af[4][2], bfr[4][2];
#pragma unroll
    for (int t = 0; t < 4; ++t)
#pragma unroll
      for (int kc = 0; kc < 2; ++kc) {
        int chp = (kc * 4 + quad) ^ swz;      // swizzled chunk
        af[t][kc]  = *(const short8*)&As[(wm + t * 16 + l16) * 64 + chp * 8];
        bfr[t][kc] = *(const short8*)&Bs[(wn + t * 16 + l16) * 64 + chp * 8];
      }
#pragma unroll
    for (int kc = 0; kc < 2; ++kc)
#pragma unroll
      for (int mt = 0; mt < 4; ++mt)
#pragma unroll
        for (int nt = 0; nt < 4; ++nt)
          acc[mt][nt] = MFMA_BF16(af[mt][kc], bfr[nt][kc], acc[mt][nt]);
  }

  const float CSCL = 0.18033688011112042f;  // (1/sqrt(64)) * log2(e)
  if (part < 2) {
    __hip_bfloat16* C = (part == 0) ? q : k;
    const float scl = (part == 0) ? CSCL : 1.0f;
#pragma unroll
    for (int mt = 0; mt < 4; ++mt)
#pragma unroll
      for (int nt = 0; nt < 4; ++nt) {
        int row = m0 + wm + mt * 16 + quad * 4;
        int col = n0 + wn + nt * 16 + l16;
#pragma unroll
        for (int r = 0; r < 4; ++r)
          C[(size_t)(row + r) * 1024 + col] = __float2bfloat16(acc[mt][nt][r] * scl);
      }
  } else {
#pragma unroll
    for (int mt = 0; mt < 4; ++mt) {
      // sigma^{-1}: own-lane kpos run mt*16+quad*4+r lands at column
      // (mt>>1)*32 + quad*8 + (mt&1)*4 + r  (bijective within 64-block)
      int rowp = m0 + wm + (mt >> 1) * 32 + quad * 8 + (mt & 1) * 4;
#pragma unroll
      for (int nt = 0; nt < 4; ++nt) {
        int nn = n0 + wn + nt * 16 + l16;
        __align__(8) __hip_bfloat16 p4[4];
#pragma unroll
        for (int r = 0; r < 4; ++r) p4[r] = __float2bfloat16(acc[mt][nt][r]);
        *(ushort4*)(vT + (size_t)nn * 8192 + rowp) = *(const ushort4*)p4;
      }
    }
  }
}

// ---------------- pipe-A deep K-loop (K=1024, BK=64) for gemm_bt ------------
// BM=256,BN=128, 512 thr (8 waves 4Mx2N, per-wave 64x64). 3 LDS slots.
// Tile t in slot t%3, staged during tile t-2; vmcnt(6) once per tile.
__device__ __forceinline__ void gemm8p_kloop(
    const __hip_bfloat16* __restrict__ A, const __hip_bfloat16* __restrict__ Bt,
    int m0, int gn0, __hip_bfloat16* As_, __hip_bfloat16* Bs_,
    f32x4 (&acc)[4][4]) {
  const int tid = threadIdx.x;
  const int lane = tid & 63, wid = tid >> 6;
  const int quad = lane >> 4, l16 = lane & 15;
  const int wm = (wid >> 1) * 64, wn = (wid & 1) * 64;
  const int sw = l16 & 7;

  // stage one half (A: 2x16B, B: 1x16B per thread) of tile t into slot
  auto stage_half = [&](int t, int half, int slot) {
#pragma unroll
    for (int li = 0; li < 2; ++li) {
      int sbase = __builtin_amdgcn_readfirstlane((half * 2 + li) * 512 + wid * 64);
      int s = sbase + lane, row = s >> 3, ch = (s & 7) ^ (row & 7);
      gld_lds16(A + (size_t)(m0 + row) * 1024 + t * 64 + ch * 8,
                As_ + slot * 16384 + sbase * 8);
    }
    {
      int sbase = __builtin_amdgcn_readfirstlane(half * 512 + wid * 64);
      int s = sbase + lane, row = s >> 3, ch = (s & 7) ^ (row & 7);
      gld_lds16(Bt + (size_t)(gn0 + row) * 1024 + t * 64 + ch * 8,
                Bs_ + slot * 8192 + sbase * 8);
    }
  };

  // one tile = 2 phases. mode 0: stage tile t+2 + vmcnt(6) at end;
  // mode 1: no stage, vmcnt(0) at end; mode 2: tail, no stage/waits/barriers.
  auto tile_step = [&](int t, int cur, int st, int mode) {
    const __hip_bfloat16* Asl = As_ + cur * 16384;
    const __hip_bfloat16* Bsl = Bs_ + cur * 8192;
    short8 af[4][2], bf01[2][2], bf23[2][2];
    // ---- phase even: read A(all m) + B(n0,n1); stage half 0 ----
#pragma unroll
    for (int mt = 0; mt < 4; ++mt)
#pragma unroll
      for (int kc = 0; kc < 2; ++kc)
        af[mt][kc] = *(const short8*)&Asl[(wm + mt * 16 + l16) * 64 +
                                          (((kc * 4 + quad) ^ sw) << 3)];
#pragma unroll
    for (int nt = 0; nt < 2; ++nt)
#pragma unroll
      for (int kc = 0; kc < 2; ++kc)
        bf01[nt][kc] = *(const short8*)&Bsl[(wn + nt * 16 + l16) * 64 +
                                            (((kc * 4 + quad) ^ sw) << 3)];
    if (mode == 0) stage_half(t + 2, 0, st);
    if (mode != 2) SBAR();
    __builtin_amdgcn_s_setprio(1);
#pragma unroll
    for (int kc = 0; kc < 2; ++kc)
#pragma unroll
      for (int mt = 0; mt < 4; ++mt)
#pragma unroll
        for (int nt = 0; nt < 2; ++nt)
          acc[mt][nt] = MFMA_BF16(af[mt][kc], bf01[nt][kc], acc[mt][nt]);
    __builtin_amdgcn_s_setprio(0);
    if (mode != 2) SBAR();
    // ---- phase odd: read B(n2,n3); stage half 1 ----
#pragma unroll
    for (int nt = 0; nt < 2; ++nt)
#pragma unroll
      for (int kc = 0; kc < 2; ++kc)
        bf23[nt][kc] = *(const short8*)&Bsl[(wn + (2 + nt) * 16 + l16) * 64 +
                                            (((kc * 4 + quad) ^ sw) << 3)];
    if (mode == 0) stage_half(t + 2, 1, st);
    if (mode != 2) SBAR();
    __builtin_amdgcn_s_setprio(1);
#pragma unroll
    for (int kc = 0; kc < 2; ++kc)
#pragma unroll
      for (int mt = 0; mt < 4; ++mt)
#pragma unroll
        for (int nt = 0; nt < 2; ++nt)
          acc[mt][2 + nt] = MFMA_BF16(af[mt][kc], bf23[nt][kc], acc[mt][2 + nt]);
    __builtin_amdgcn_s_setprio(0);
    if (mode == 0) VMCNT6();
    if (mode == 1) VMCNT0();
    if (mode != 2) SBAR();
  };

  // prologue: stage tile 0 -> slot 0, tile 1 -> slot 1 (6 loads each)
#pragma unroll
  for (int h = 0; h < 2; ++h) stage_half(0, h, 0);
#pragma unroll
  for (int h = 0; h < 2; ++h) stage_half(1, h, 1);
  VMCNT6();   // 12 in flight -> wait for oldest 6 = tile 0 landed
  SBAR();

  int cur = 0, st = 2;
#pragma unroll 1
  for (int t = 0; t < 14; ++t) {
    tile_step(t, cur, st, 0);
    cur = (cur == 2) ? 0 : cur + 1;
    st = (st == 2) ? 0 : st + 1;
  }
  tile_step(14, 2, 0, 1);   // drain remaining (tile 15) loads at end
  tile_step(15, 0, 0, 2);   // pure compute, no syncs needed after
}

// --------------- final GEMM: out = ctx * woT^T + bias (fp32 out) -----------
// grid (8, 32): n0 = x*128, m0 = y*256 -> 256 blocks = exactly 1 round.
__global__ __launch_bounds__(512, 2) void gemm_bt_f32out(
    const __hip_bfloat16* __restrict__ A, const __hip_bfloat16* __restrict__ Bt,
    float* __restrict__ C, const float* __restrict__ bias) {
  __shared__ __align__(16) __hip_bfloat16 As[3 * 256 * 64];
  __shared__ __align__(16) __hip_bfloat16 Bs[3 * 128 * 64];
  const int tid = threadIdx.x;
  const int lane = tid & 63, wid = tid >> 6;
  const int quad = lane >> 4, l16 = lane & 15;
  const int n0 = blockIdx.x * 128, m0 = blockIdx.y * 256;
  const int wm = (wid >> 1) * 64, wn = (wid & 1) * 64;

  f32x4 acc[4][4] = {};
  gemm8p_kloop(A, Bt, m0, n0, As, Bs, acc);

#pragma unroll
  for (int mt = 0; mt < 4; ++mt)
#pragma unroll
    for (int nt = 0; nt < 4; ++nt) {
      int row = m0 + wm + mt * 16 + quad * 4;
      int col = n0 + wn + nt * 16 + l16;
      float b = bias[col];
#pragma unroll
      for (int r = 0; r < 4; ++r)
        C[(size_t)(row + r) * 1024 + col] = acc[mt][nt][r] + b;
    }
}

// ----------------------------- flash attention ------------------------------
// R17 structure: 16 q-tiles of 128 rows, paired (t,15-t), 34 uniform iters,
// grid 512, 4 waves x 32 q-rows. Swapped QK^T -> lane holds S^T. P never
// touches LDS OR crosses lanes: A-frag slot (kc,j) = exp2(sv[mt][2kc+(j>>2)]
// [j&3]) (sigma k-reindex; V pre-permuted by gemm_qkv to match).
// K/V double-buffered gld_lds staging, one barrier/iter, XOR-swizzled LDS.
__global__ __launch_bounds__(256, 2) void attn_kernel(
    const __hip_bfloat16* __restrict__ Q, const __hip_bfloat16* __restrict__ Km,
    const __hip_bfloat16* __restrict__ vT, __hip_bfloat16* __restrict__ ctx) {
  const int bid = blockIdx.x;
  // XCD-grouped remap: each XCD owns 8 full (b,h) streams (~4MB = its L2).
  const int xcd = bid & 7, loc = bid >> 3;
  const int grp = xcd * 8 + (loc >> 3);     // b*16 + h
  const int p = loc & 7;                    // pair index
  const int h = grp & 15, b = grp >> 4;
  const size_t rbase = (size_t)b * 2048;
  const int tid = threadIdx.x, lane = tid & 63, wid = tid >> 6;
  const int quad = lane >> 4, l16 = lane & 15;
  const int sw = l16 & 7;                   // fragment-row swizzle (row&7)

  __shared__ __align__(16) __hip_bfloat16 Ks[2][64 * 64];   // dbuf [kpos][swz]
  __shared__ __align__(16) __hip_bfloat16 Vs[2][64 * 64];   // dbuf [d][swz]

  const float NEG_BIG = -1e30f;             // exp2 -> exactly 0

#pragma unroll 1
  for (int sub = 0; sub < 2; ++sub) {
    const int t = sub ? (15 - p) : p;       // 128-row q-tile index
    const int q0 = t * 128;
    const int qw = q0 + wid * 32;           // wave's 32-row base
    const int nkt = 2 * t + 2;              // k-tiles this q-tile needs

    __syncthreads();  // all waves done reading LDS from previous sub
    {  // prologue: issue stage of k-tile 0 into buffer 0 (async)
#pragma unroll
      for (int i = 0; i < 2; ++i) {
        int sbase = __builtin_amdgcn_readfirstlane(i * 256 + wid * 64);
        int s = sbase + lane, row = s >> 3, lch = (s & 7) ^ (row & 7);
        gld_lds16(Km + (rbase + row) * 1024 + h * 64 + lch * 8, &Ks[0][sbase * 8]);
        gld_lds16(vT + (size_t)(h * 64 + row) * 8192 + rbase + lch * 8, &Vs[0][sbase * 8]);
      }
    }

    short8 qf[2][2];
#pragma unroll
    for (int mt = 0; mt < 2; ++mt)
#pragma unroll
      for (int kc = 0; kc < 2; ++kc)
        qf[mt][kc] = *(const short8*)(Q + (rbase + qw + mt * 16 + l16) * 1024 +
                                      h * 64 + kc * 32 + quad * 8);

    f32x4 o[2][4] = {};
    float lp[2] = {0.f, 0.f};               // per-lane row sums (row = l16)

#pragma unroll 1
    for (int kt = 0; kt < nkt; ++kt) {
      const int cur = kt & 1;
      const int kbase = kt * 64;
      // ONE barrier: stage(kt) landed (vmcnt drained by compiler here), and
      // all waves' reads of buf[cur^1] (iter kt-1) are done.
      __syncthreads();
      if (kt + 1 < nkt) {  // issue stage(kt+1) into the other buffer (async)
        const int kb = kbase + 64;
#pragma unroll
        for (int i = 0; i < 2; ++i) {
          int sbase = __builtin_amdgcn_readfirstlane(i * 256 + wid * 64);
          int s = sbase + lane, row = s >> 3, lch = (s & 7) ^ (row & 7);
          gld_lds16(Km + (rbase + kb + row) * 1024 + h * 64 + lch * 8,
                    &Ks[cur ^ 1][sbase * 8]);
          gld_lds16(vT + (size_t)(h * 64 + row) * 8192 + rbase + kb + lch * 8,
                    &Vs[cur ^ 1][sbase * 8]);
        }
      }
      const __hip_bfloat16* Kb = &Ks[cur][0];
      const __hip_bfloat16* Vb = &Vs[cur][0];

      if (kbase <= qw + 31) {  // wave-uniform: skip fully-masked tiles
        // K fragments (A-operand), reused for both mt
        short8 kf[4][2];
#pragma unroll
        for (int nt = 0; nt < 4; ++nt)
#pragma unroll
          for (int kc = 0; kc < 2; ++kc)
            kf[nt][kc] = *(const short8*)&Kb[(nt * 16 + l16) * 64 +
                                             (((kc * 4 + quad) ^ sw) << 3)];
        // S^T = K * Q^T: sv[mt][nt] has kpos=quad*4+r (+16nt), qrow=l16 (+16mt)
        f32x4 sv[2][4];
#pragma unroll
        for (int mt = 0; mt < 2; ++mt)
#pragma unroll
          for (int nt = 0; nt < 4; ++nt) {
            f32x4 z = {0.f, 0.f, 0.f, 0.f};
            z = MFMA_BF16(kf[nt][0], qf[mt][0], z);
            z = MFMA_BF16(kf[nt][1], qf[mt][1], z);
            sv[mt][nt] = z;
          }
        if (kbase + 63 > qw) {  // causal mask, diagonal-band tiles only
#pragma unroll
          for (int mt = 0; mt < 2; ++mt)
#pragma unroll
            for (int nt = 0; nt < 4; ++nt)
#pragma unroll
              for (int r = 0; r < 4; ++r) {
                int kpos = kbase + nt * 16 + quad * 4 + r;
                int qrow = qw + mt * 16 + l16;
                if (kpos > qrow) sv[mt][nt][r] = NEG_BIG;
              }
        }
        // p = exp2(s); assemble PV A-frags from OWN lane values only:
        // A-frag slot (kc, j) = p[nt = 2kc + (j>>2)][r = j&3]
        // (sigma k-reindex, matched by gemm_qkv's permuted vT columns).
        short8 pa[2][2];
#pragma unroll
        for (int mt = 0; mt < 2; ++mt)
#pragma unroll
          for (int kc = 0; kc < 2; ++kc) {
            __align__(16) __hip_bfloat16 pb[8];
#pragma unroll
            for (int half = 0; half < 2; ++half) {
              int nt = 2 * kc + half;
#pragma unroll
              for (int r = 0; r < 4; ++r) {
                float pv = __builtin_amdgcn_exp2f(sv[mt][nt][r]);
                lp[mt] += pv;
                pb[half * 4 + r] = __float2bfloat16(pv);
              }
            }
            pa[mt][kc] = *(const short8*)pb;
          }
        // PV: A = P (in-register), B = V (sigma-permuted tile), b128 reads
        short8 vf[4][2];
#pragma unroll
        for (int dt = 0; dt < 4; ++dt)
#pragma unroll
          for (int kc = 0; kc < 2; ++kc)
            vf[dt][kc] = *(const short8*)&Vb[(dt * 16 + l16) * 64 +
                                             (((kc * 4 + quad) ^ sw) << 3)];
#pragma unroll
        for (int mt = 0; mt < 2; ++mt)
#pragma unroll
          for (int dt = 0; dt < 4; ++dt) {
            o[mt][dt] = MFMA_BF16(pa[mt][0], vf[dt][0], o[mt][dt]);
            o[mt][dt] = MFMA_BF16(pa[mt][1], vf[dt][1], o[mt][dt]);
          }
      }
    }

    // lp[mt] holds partials for row mt*16+l16 spread across quads: reduce,
    // then redistribute to the C-layout rows (quad*4+r) via computed shfl.
#pragma unroll
    for (int mt = 0; mt < 2; ++mt) {
      lp[mt] += __shfl_xor(lp[mt], 16, 64);
      lp[mt] += __shfl_xor(lp[mt], 32, 64);
    }
#pragma unroll
    for (int mt = 0; mt < 2; ++mt) {
      float inv[4];
#pragma unroll
      for (int r = 0; r < 4; ++r)
        inv[r] = 1.f / __shfl(lp[mt], quad * 4 + r, 64);
#pragma unroll
      for (int dt = 0; dt < 4; ++dt)
#pragma unroll
        for (int r = 0; r < 4; ++r)
          ctx[(rbase + qw + mt * 16 + quad * 4 + r) * 1024 + h * 64 + dt * 16 + l16] =
              __float2bfloat16(o[mt][dt][r] * inv[r]);
    }
  }
}

// ------------------------------- launcher ----------------------------------
extern "C" void kernel_launch(void* const* d_in, const int* in_sizes, int n_in,
                              void* d_out, int out_size, void* d_ws, size_t ws_size,
                              hipStream_t stream) {
  const float* x  = (const float*)d_in[0];
  const float* Wq = (const float*)d_in[1];
  const float* Wk = (const float*)d_in[2];
  const float* Wv = (const float*)d_in[3];
  const float* Wo = (const float*)d_in[4];
  const float* bo = (const float*)d_in[5];
  float* out = (float*)d_out;

  char* ws = (char*)d_ws;
  const size_t MB = 1024ull * 1024ull;
  __hip_bfloat16* q   = (__hip_bfloat16*)(ws);             // 16 MB (reused as ctx)
  __hip_bfloat16* k   = (__hip_bfloat16*)(ws + 16 * MB);   // 16 MB
  __hip_bfloat16* vT  = (__hip_bfloat16*)(ws + 32 * MB);   // 16 MB, [h*64+d][b*2048+s]
  __hip_bfloat16* woT = (__hip_bfloat16*)(ws + 48 * MB);   // 2 MB -> 50 MB total
  __hip_bfloat16* ctx = q;  // attention reads its Q region before writing it

  // Pre-final scratch inside d_out's 32MB fp32 buffer (stream-ordered reuse):
  char* outc = (char*)d_out;
  __hip_bfloat16* xb    = (__hip_bfloat16*)(outc);            // [0, 16 MB)
  __hip_bfloat16* wcatT = (__hip_bfloat16*)(outc + 16 * MB);  // [16, 22 MB)

  prep_kernel<<<8192 + 4096, 256, 0, stream>>>(
      x, xb, Wq, Wk, Wv, Wo,
      wcatT, wcatT + 1024 * 1024, wcatT + 2048 * 1024, woT);

  gemm_qkv<<<dim3(24, 64), 256, 0, stream>>>(xb, wcatT, q, k, vT);

  attn_kernel<<<512, 256, 0, stream>>>(q, k, vT, ctx);

  gemm_bt_f32out<<<dim3(8, 32), 512, 0, stream>>>(ctx, woT, out, bo);
}